// Round 1
// baseline (1707.195 us; speedup 1.0000x reference)
//
#include <hip/hip_runtime.h>
#include <hip/hip_bf16.h>
#include <math.h>

// Problem constants (from reference setup_inputs)
#define BB 16
#define DD 40
#define NN 64512
#define KK 4

#define ALPHA 5.0f
#define N_ITERS 10
#define EPS_KM 1e-9f

// ---------------------------------------------------------------------------
// Kernel 1: Vact = tanh(V), vectorized float4. B*D*N = 41287680 (div by 4).
// ---------------------------------------------------------------------------
__global__ __launch_bounds__(256) void tanh_kernel(const float4* __restrict__ V,
                                                   float4* __restrict__ Vact,
                                                   int n4) {
    int i = blockIdx.x * 256 + threadIdx.x;
    if (i < n4) {
        float4 x = V[i];
        float4 y;
        y.x = tanhf(x.x);
        y.y = tanhf(x.y);
        y.z = tanhf(x.z);
        y.w = tanhf(x.w);
        Vact[i] = y;
    }
}

// ---------------------------------------------------------------------------
// Kernel 2: init U0[b,k,d] = tanh(V[b,d,idx[b,k]]); compute u2; zero accums.
// Single block, 256 threads.
// ---------------------------------------------------------------------------
__global__ __launch_bounds__(256) void init_kernel(const float* __restrict__ V,
                                                   const int* __restrict__ idx,
                                                   float* __restrict__ U,
                                                   float* __restrict__ accV,
                                                   float* __restrict__ accS,
                                                   float* __restrict__ u2) {
    const int tid = threadIdx.x;
    for (int i = tid; i < BB * KK * DD; i += 256) {
        int b = i / (KK * DD);
        int r = i - b * (KK * DD);
        int k = r / DD;
        int d = r - k * DD;
        int n0 = idx[b * KK + k];
        U[i] = tanhf(V[(b * DD + d) * NN + n0]);
        accV[i] = 0.f;
    }
    __syncthreads();
    if (tid < BB * KK) {
        float s = 0.f;
        for (int d = 0; d < DD; ++d) {
            float x = U[tid * DD + d];
            s = fmaf(x, x, s);
        }
        u2[tid] = s;
        accS[tid] = 0.f;
    }
}

// ---------------------------------------------------------------------------
// Kernel 3: one k-means iteration (the hot kernel).
// grid = (63, B). Block = 256 threads = 4 waves. Wave w owns d in [10w,10w+10).
// Each step handles 64 n's (lane l <-> n). Per-step cross-wave partial-sum
// reduction goes through ping-pong LDS with ONE barrier per step.
// Per-thread accumulators acc[4][10] (its wave's d-slice), reduced across the
// 64 lanes at the end, then atomicAdd into global accumulators.
// ---------------------------------------------------------------------------
__global__ __launch_bounds__(256) void km_iter_kernel(const float* __restrict__ Vact,
                                                      const float* __restrict__ U,
                                                      const float* __restrict__ u2,
                                                      float* __restrict__ accV,
                                                      float* __restrict__ accS) {
    __shared__ float sU[KK * DD];
    __shared__ float su2[KK];
    __shared__ float part[2][4][64][5];  // [buf][wave][lane][c0..c3, v2]

    const int tid = threadIdx.x;
    const int w = tid >> 6;   // wave id 0..3
    const int l = tid & 63;   // lane
    const int b = blockIdx.y;
    const int d0 = w * 10;

    for (int i = tid; i < KK * DD; i += 256) sU[i] = U[b * KK * DD + i];
    if (tid < KK) su2[tid] = u2[b * KK + tid];
    __syncthreads();

    // cache centroid slice + u2 in registers
    float uk[KK][10];
#pragma unroll
    for (int k = 0; k < KK; ++k)
#pragma unroll
        for (int j = 0; j < 10; ++j) uk[k][j] = sU[k * DD + d0 + j];
    float u2r[KK];
#pragma unroll
    for (int k = 0; k < KK; ++k) u2r[k] = su2[k];

    float acc[KK][10];
#pragma unroll
    for (int k = 0; k < KK; ++k)
#pragma unroll
        for (int j = 0; j < 10; ++j) acc[k][j] = 0.f;
    float sy[KK] = {0.f, 0.f, 0.f, 0.f};

    const float* Vb = Vact + (size_t)b * (size_t)(DD * NN);
    const int nbase = blockIdx.x * 1024;  // 63 * 1024 = 64512 = N

    for (int s = 0; s < 16; ++s) {
        const int n = nbase + s * 64 + l;
        float v[10];
#pragma unroll
        for (int j = 0; j < 10; ++j) v[j] = Vb[(d0 + j) * NN + n];

        float pc0 = 0.f, pc1 = 0.f, pc2 = 0.f, pc3 = 0.f, pv = 0.f;
#pragma unroll
        for (int j = 0; j < 10; ++j) {
            const float vv = v[j];
            pv = fmaf(vv, vv, pv);
            pc0 = fmaf(uk[0][j], vv, pc0);
            pc1 = fmaf(uk[1][j], vv, pc1);
            pc2 = fmaf(uk[2][j], vv, pc2);
            pc3 = fmaf(uk[3][j], vv, pc3);
        }
        float* pp = part[s & 1][w][l];
        pp[0] = pc0; pp[1] = pc1; pp[2] = pc2; pp[3] = pc3; pp[4] = pv;
        __syncthreads();

        float c0 = 0.f, c1 = 0.f, c2 = 0.f, c3 = 0.f, v2 = 0.f;
#pragma unroll
        for (int w2 = 0; w2 < 4; ++w2) {
            const float* q = part[s & 1][w2][l];
            c0 += q[0]; c1 += q[1]; c2 += q[2]; c3 += q[3]; v2 += q[4];
        }

        const float cc[KK] = {c0, c1, c2, c3};
        float dist[KK];
        float m = -1e30f;
#pragma unroll
        for (int k = 0; k < KK; ++k) {
            float d2 = v2 + u2r[k] - 2.f * cc[k];
            dist[k] = -ALPHA * sqrtf(fmaxf(d2, 1e-12f));
            m = fmaxf(m, dist[k]);
        }
        float e[KK];
        float se = 0.f;
#pragma unroll
        for (int k = 0; k < KK; ++k) {
            e[k] = expf(dist[k] - m);
            se += e[k];
        }
        const float inv = 1.f / se;
#pragma unroll
        for (int k = 0; k < KK; ++k) {
            const float y = e[k] * inv;
            if (w == 0) sy[k] += y;  // each n counted exactly once (wave 0 only)
#pragma unroll
            for (int j = 0; j < 10; ++j) acc[k][j] = fmaf(y, v[j], acc[k][j]);
        }
        // single barrier per step is safe: ping-pong buffers — next step writes
        // the buffer last *read* two steps ago, separated by this barrier.
    }

    // reduce acc across the 64 lanes of each wave, then atomicAdd
#pragma unroll
    for (int k = 0; k < KK; ++k) {
#pragma unroll
        for (int j = 0; j < 10; ++j) {
            float val = acc[k][j];
            for (int off = 32; off > 0; off >>= 1) val += __shfl_down(val, off, 64);
            if (l == 0) atomicAdd(&accV[(b * KK + k) * DD + d0 + j], val);
        }
    }
    if (w == 0) {
#pragma unroll
        for (int k = 0; k < KK; ++k) {
            float val = sy[k];
            for (int off = 32; off > 0; off >>= 1) val += __shfl_down(val, off, 64);
            if (l == 0) atomicAdd(&accS[b * KK + k], val);
        }
    }
}

// ---------------------------------------------------------------------------
// Kernel 4: finalize U = accV/(accS+eps); recompute u2; zero accums.
// Single block, 256 threads.
// ---------------------------------------------------------------------------
__global__ __launch_bounds__(256) void km_finalize_kernel(float* __restrict__ U,
                                                          float* __restrict__ accV,
                                                          float* __restrict__ accS,
                                                          float* __restrict__ u2) {
    const int tid = threadIdx.x;
    for (int i = tid; i < BB * KK * DD; i += 256) {
        U[i] = accV[i] / (accS[i / DD] + EPS_KM);
        accV[i] = 0.f;
    }
    __syncthreads();
    if (tid < BB * KK) {
        float s = 0.f;
        for (int d = 0; d < DD; ++d) {
            float x = U[tid * DD + d];
            s = fmaf(x, x, s);
        }
        u2[tid] = s;
        accS[tid] = 0.f;
    }
}

// ---------------------------------------------------------------------------
// Kernel 5: final mask = softmax_k( A . Vact ). grid = (252, B), 256 thr.
// ---------------------------------------------------------------------------
__global__ __launch_bounds__(256) void mask_kernel(const float* __restrict__ Vact,
                                                   const float* __restrict__ U,
                                                   float* __restrict__ mask) {
    __shared__ float sA[KK * DD];
    const int tid = threadIdx.x;
    const int b = blockIdx.y;
    const int n = blockIdx.x * 256 + tid;

    for (int i = tid; i < KK * DD; i += 256) sA[i] = U[b * KK * DD + i];
    __syncthreads();

    const float* Vb = Vact + (size_t)b * (size_t)(DD * NN);
    float d0 = 0.f, d1 = 0.f, d2 = 0.f, d3 = 0.f;
    for (int d = 0; d < DD; ++d) {
        const float vv = Vb[d * NN + n];
        d0 = fmaf(sA[0 * DD + d], vv, d0);
        d1 = fmaf(sA[1 * DD + d], vv, d1);
        d2 = fmaf(sA[2 * DD + d], vv, d2);
        d3 = fmaf(sA[3 * DD + d], vv, d3);
    }
    float m = fmaxf(fmaxf(d0, d1), fmaxf(d2, d3));
    float e0 = expf(d0 - m), e1 = expf(d1 - m), e2 = expf(d2 - m), e3 = expf(d3 - m);
    float inv = 1.f / (e0 + e1 + e2 + e3);
    float* mb = mask + (size_t)b * (size_t)(KK * NN);
    mb[0 * NN + n] = e0 * inv;
    mb[1 * NN + n] = e1 * inv;
    mb[2 * NN + n] = e2 * inv;
    mb[3 * NN + n] = e3 * inv;
}

// ---------------------------------------------------------------------------
// Kernel 6: copy A (=U after 10 iters) to the output tail.
// ---------------------------------------------------------------------------
__global__ __launch_bounds__(256) void copyA_kernel(const float* __restrict__ U,
                                                    float* __restrict__ Aout) {
    int i = blockIdx.x * 256 + threadIdx.x;
    if (i < BB * KK * DD) Aout[i] = U[i];
}

// ---------------------------------------------------------------------------
extern "C" void kernel_launch(void* const* d_in, const int* in_sizes, int n_in,
                              void* d_out, int out_size, void* d_ws, size_t ws_size,
                              hipStream_t stream) {
    const float* V = (const float*)d_in[0];
    const int* idx = (const int*)d_in[1];

    float* out = (float*)d_out;
    float* mask = out;                                   // B*K*N
    float* Vact = out + (size_t)BB * KK * NN;            // B*D*N
    float* Aout = Vact + (size_t)BB * DD * NN;           // B*K*D

    float* ws = (float*)d_ws;
    float* U    = ws;            // 2560
    float* accV = ws + 2560;     // 2560
    float* accS = ws + 5120;     // 64
    float* u2   = ws + 5184;     // 64

    const int n4 = (BB * DD * NN) / 4;  // 10321920
    tanh_kernel<<<dim3((n4 + 255) / 256), dim3(256), 0, stream>>>(
        (const float4*)V, (float4*)Vact, n4);
    init_kernel<<<dim3(1), dim3(256), 0, stream>>>(V, idx, U, accV, accS, u2);

    for (int it = 0; it < N_ITERS; ++it) {
        km_iter_kernel<<<dim3(63, BB), dim3(256), 0, stream>>>(Vact, U, u2, accV, accS);
        km_finalize_kernel<<<dim3(1), dim3(256), 0, stream>>>(U, accV, accS, u2);
    }

    mask_kernel<<<dim3(NN / 256, BB), dim3(256), 0, stream>>>(Vact, U, mask);
    copyA_kernel<<<dim3(10), dim3(256), 0, stream>>>(U, Aout);
}